// Round 14
// baseline (24.634 us; speedup 1.0000x reference)
//
#include <hip/hip_runtime.h>
#include <hip/hip_bf16.h>
#include <math.h>

// R14: cross-tile software pipeline (T14 async-stage split).
// R13 analysis: replay-time L3 is thrashed by harness fills -> x comes from
// HBM cold, but our burst-then-silent load pattern sustains only ~0.8 TB/s
// (fills prove 6.7). Fix: block = 8 rows x 64 px (10-row halo, 55.4 KB LDS),
// 512 blocks = 2/CU single generation, launch_bounds(256,2) -> VGPR cap 256.
// Schedule: issue rows0-5 -> write LDS -> issue wa + rows6-9 -> barrier ->
// compute tileA (rows6-9 STILL IN FLIGHT; wa waits leave them outstanding)
// -> write rows6-9 -> barrier -> compute tileB. Halo rows 4-5 staged once.

#define ALPHA_F 8.3f

constexpr int B_    = 4;
constexpr int CIN   = 32;
constexpr int COUT  = 32;
constexpr int H_    = 256;
constexpr int W_    = 256;
constexpr int KTAPS = 9;
constexpr int HW    = H_ * W_;

typedef __attribute__((ext_vector_type(8))) short bf16x8;
typedef __attribute__((ext_vector_type(4))) float f32x4;

static __device__ __forceinline__ short f2bf(float f) {
    __hip_bfloat16 h = __float2bfloat16(f);
    return __builtin_bit_cast(short, h);
}

// ---- prep: weights into per-lane A-fragment layout (verified R2-R13) ----
__global__ void prep_wfrag(const float* __restrict__ w, short* __restrict__ wf) {
    int idx = blockIdx.x * 256 + threadIdx.x;
    if (idx >= KTAPS * 2 * 64 * 8) return;
    int e  = idx & 7;
    int l  = (idx >> 3) & 63;
    int t  = (idx >> 9) & 1;
    int ij = idx >> 10;
    int o  = t * 16 + (l & 15);
    int c  = (l >> 4) * 8 + e;
    wf[idx] = f2bf(w[(o * CIN + c) * KTAPS + ij]);
}

// ---- fused main kernel: 8 rows x 64 px, 2-tile pipelined ----
__global__ __launch_bounds__(256, 2)
void dconv_fused10(const float* __restrict__ x,
                   const float* __restrict__ depth,
                   const short* __restrict__ wf,
                   float* __restrict__ out) {
    __shared__ __align__(16) short xs[10][66][40];  // 52,800 B bf16 x tile
    __shared__ float dsh[10][66];                   //  2,640 B depth stencil

    // XCD-bijective swizzle: 512 blocks, 512 % 8 == 0
    const int bid  = (int)blockIdx.x;
    const int bswz = (bid & 7) * 64 + (bid >> 3);

    const int b    = bswz >> 7;          // image (4)
    const int hseg = (bswz >> 2) & 31;   // 32 row-groups of 8
    const int wseg = (bswz & 3) << 6;    // 4 col segments of 64 px
    const int h0   = hseg << 3;          // first output row
    const int tid  = threadIdx.x;
    const int lane = tid & 63;
    const float* xb  = x + (size_t)b * CIN * HW;
    const float* dpl = depth + (size_t)b * HW;

    // ========== STAGE-1 ISSUE: rows lr 0..5 (grows h0-1 .. h0+4) ==========
    float xv0[24], xv1[24];
#pragma unroll
    for (int it = 0; it < 24; ++it) {
        const int idx = it * 256 + tid;
        const int q   = idx & 63;
        const int cp  = (idx >> 6) & 15;
        const int r   = idx >> 10;                   // 0..5
        const int row = h0 + r - 1;
        const int rowc = ((unsigned)row < (unsigned)H_) ? row : h0;  // clamp
        const size_t gb = (size_t)(2 * cp) * HW + rowc * W_ + wseg + q;
        xv0[it] = xb[gb];
        xv1[it] = xb[gb + HW];
    }
    float hv0, hv1;
    {
        const int side = tid & 1;
        const int hrc  = tid >> 1;
        const int hcp  = hrc & 15;
        const int hr   = (hrc >> 4) % 6;
        const int hrow = h0 + hr - 1;
        const int hwx  = wseg - 1 + side * 65;
        const bool hok = (tid < 192) &&
                         ((unsigned)hrow < (unsigned)H_) &&
                         ((unsigned)hwx  < (unsigned)W_);
        const size_t gb = (size_t)(2 * hcp) * HW +
                          (hok ? (size_t)(hrow * W_ + hwx) : 0);
        hv0 = xb[gb];
        hv1 = xb[gb + HW];
    }
    float dv0, dv1;
    {
        const int r0   = tid / 66;                   // 0..3
        const int q0   = tid - r0 * 66;
        const int row0 = h0 + r0 - 1;
        const int wx0  = wseg - 1 + q0;
        const bool ok0 = ((unsigned)row0 < (unsigned)H_) &&
                         ((unsigned)wx0  < (unsigned)W_);
        dv0 = dpl[ok0 ? (row0 * W_ + wx0) : 0];

        const int k1   = tid + 256;
        const int r1   = (k1 / 66) % 6;
        const int q1   = k1 - (k1 / 66) * 66;
        const int row1 = h0 + r1 - 1;
        const int wx1  = wseg - 1 + q1;
        const bool ok1 = (k1 < 396) &&
                         ((unsigned)row1 < (unsigned)H_) &&
                         ((unsigned)wx1  < (unsigned)W_);
        dv1 = dpl[ok1 ? (row1 * W_ + wx1) : 0];
    }

    // ========== STAGE-1 WRITE: convert + LDS ==========
#pragma unroll
    for (int it = 0; it < 24; ++it) {
        const int idx = it * 256 + tid;
        const int q   = idx & 63;
        const int cp  = (idx >> 6) & 15;
        const int r   = idx >> 10;
        const bool ok = ((unsigned)(h0 + r - 1) < (unsigned)H_);
        const float f0 = ok ? xv0[it] : 0.f;
        const float f1 = ok ? xv1[it] : 0.f;
        const int v = (int)(unsigned short)f2bf(f0) |
                      ((int)(unsigned short)f2bf(f1) << 16);
        ((int*)&xs[r][q + 1][0])[cp] = v;
    }
    if (tid < 192) {
        const int side = tid & 1;
        const int hrc  = tid >> 1;
        const int hcp  = hrc & 15;
        const int hr   = hrc >> 4;                   // 0..5
        const int hrow = h0 + hr - 1;
        const int hwx  = wseg - 1 + side * 65;
        const bool hok = ((unsigned)hrow < (unsigned)H_) &&
                         ((unsigned)hwx  < (unsigned)W_);
        const float f0 = hok ? hv0 : 0.f;
        const float f1 = hok ? hv1 : 0.f;
        const int v = (int)(unsigned short)f2bf(f0) |
                      ((int)(unsigned short)f2bf(f1) << 16);
        ((int*)&xs[hr][side * 65][0])[hcp] = v;
    }
    {
        const int r0 = tid / 66;
        const int q0 = tid - r0 * 66;
        const bool ok0 = ((unsigned)(h0 + r0 - 1) < (unsigned)H_) &&
                         ((unsigned)(wseg - 1 + q0) < (unsigned)W_);
        dsh[r0][q0] = ok0 ? dv0 : 0.f;
        const int k1 = tid + 256;
        if (k1 < 396) {
            const int r1 = k1 / 66;
            const int q1 = k1 - r1 * 66;
            const bool ok1 = ((unsigned)(h0 + r1 - 1) < (unsigned)H_) &&
                             ((unsigned)(wseg - 1 + q1) < (unsigned)W_);
            dsh[r1][q1] = ok1 ? dv1 : 0.f;
        }
    }

    // ========== wa ISSUE (first!), then STAGE-2 ISSUE rows lr 6..9 ========
    // wa issued before stage-2 loads: computeA's wa-wait leaves stage-2
    // loads outstanding -> they drain under computeA.
    const bf16x8* wfv = (const bf16x8*)wf;
    bf16x8 wa[2 * KTAPS];
#pragma unroll
    for (int k = 0; k < 2 * KTAPS; ++k) wa[k] = wfv[k * 64 + lane];

    // stage-2: 4 rows x 16 ch-pairs x 64 px = 4096 pairs, 16/thread
    float yv0[16], yv1[16];
#pragma unroll
    for (int it = 0; it < 16; ++it) {
        const int idx = it * 256 + tid;
        const int q   = idx & 63;
        const int cp  = (idx >> 6) & 15;
        const int r2  = idx >> 10;                   // 0..3
        const int row = h0 + 5 + r2;
        const int rowc = ((unsigned)row < (unsigned)H_) ? row : h0;  // clamp
        const size_t gb = (size_t)(2 * cp) * HW + rowc * W_ + wseg + q;
        yv0[it] = xb[gb];
        yv1[it] = xb[gb + HW];
    }
    float hw0, hw1;
    {
        const int side = tid & 1;
        const int hrc  = tid >> 1;                   // 0..63 used
        const int hcp  = hrc & 15;
        const int hr2  = (hrc >> 4) & 3;             // 0..3
        const int hrow = h0 + 5 + hr2;
        const int hwx  = wseg - 1 + side * 65;
        const bool hok = (tid < 128) &&
                         ((unsigned)hrow < (unsigned)H_) &&
                         ((unsigned)hwx  < (unsigned)W_);
        const size_t gb = (size_t)(2 * hcp) * HW +
                          (hok ? (size_t)(hrow * W_ + hwx) : 0);
        hw0 = xb[gb];
        hw1 = xb[gb + HW];
    }
    float dw0, dw1;
    {
        const int r0   = tid / 66;                   // 0..3
        const int q0   = tid - r0 * 66;
        const int row0 = h0 + 5 + r0;
        const int wx0  = wseg - 1 + q0;
        const bool ok0 = ((unsigned)row0 < (unsigned)H_) &&
                         ((unsigned)wx0  < (unsigned)W_);
        dw0 = dpl[ok0 ? (row0 * W_ + wx0) : 0];

        const int k1   = tid + 256;                  // 256..263 used
        const int q1   = k1 - 198;                   // k1<264 -> row lr9, q=k1-198... 
        // careful: stage-2 dsh rows are lr 6..9 -> 4*66=264 values, k in [0,264)
        // k = tid covers 0..255; k1 = tid+256 covers 256..263 (8 threads)
        const int r1   = (k1 / 66) & 3;              // 3 for k1 in 256..263... (k1/66=3)
        const int q1b  = k1 - (k1 / 66) * 66;
        const int row1 = h0 + 5 + r1;
        const int wx1  = wseg - 1 + q1b;
        const bool ok1 = (k1 < 264) &&
                         ((unsigned)row1 < (unsigned)H_) &&
                         ((unsigned)wx1  < (unsigned)W_);
        (void)q1;
        dw1 = dpl[ok1 ? (row1 * W_ + wx1) : 0];
    }

    __syncthreads();   // xs rows 0..5 + dsh rows 0..5 ready

    // ========== COMPUTE TILE A (out rows h0..h0+3), stage-2 in flight =====
    const int w    = tid >> 6;           // 0..3
    const int n    = lane & 15;
    const int cg   = (lane >> 4) * 8;
    const int orow = (lane >> 4) * 4;
    const f32x4 z = {0.f, 0.f, 0.f, 0.f};

    {
        const int rl   = w + 1;
        const int hrow = h0 + w;
#pragma unroll
        for (int sub = 0; sub < 4; ++sub) {
            const int pl = sub * 16 + n + 1;
            const int wp = wseg + sub * 16 + n;
            const float dc = dsh[rl][pl];

            float s[KTAPS];
#pragma unroll
            for (int ij = 0; ij < KTAPS; ++ij) {
                const int di = ij / 3 - 1;
                const int dj = ij % 3 - 1;
                const bool ok = ((unsigned)(hrow + di) < (unsigned)H_) &&
                                ((unsigned)(wp + dj) < (unsigned)W_);
                s[ij] = ok ? __expf(-ALPHA_F * fabsf(dc - dsh[rl + di][pl + dj])) : 0.f;
            }

            f32x4 acc0 = z, acc1 = z;
#pragma unroll
            for (int ij = 0; ij < KTAPS; ++ij) {
                const int di = ij / 3 - 1;
                const int dj = ij % 3 - 1;
                const bf16x8 bfrag = *(const bf16x8*)&xs[rl + di][pl + dj][cg];
                const f32x4 t0 = __builtin_amdgcn_mfma_f32_16x16x32_bf16(wa[ij * 2 + 0], bfrag, z, 0, 0, 0);
                const f32x4 t1 = __builtin_amdgcn_mfma_f32_16x16x32_bf16(wa[ij * 2 + 1], bfrag, z, 0, 0, 0);
#pragma unroll
                for (int j = 0; j < 4; ++j) {
                    acc0[j] = fmaf(s[ij], t0[j], acc0[j]);
                    acc1[j] = fmaf(s[ij], t1[j], acc1[j]);
                }
            }

            float* ob = out + (size_t)b * COUT * HW + hrow * W_ + wp;
#pragma unroll
            for (int j = 0; j < 4; ++j) {
                __builtin_nontemporal_store(acc0[j], ob + (size_t)(orow + j) * HW);
                __builtin_nontemporal_store(acc1[j], ob + (size_t)(orow + j + 16) * HW);
            }
        }
    }

    // ========== STAGE-2 WRITE: convert + LDS rows 6..9 ==========
#pragma unroll
    for (int it = 0; it < 16; ++it) {
        const int idx = it * 256 + tid;
        const int q   = idx & 63;
        const int cp  = (idx >> 6) & 15;
        const int r2  = idx >> 10;                   // 0..3
        const bool ok = ((unsigned)(h0 + 5 + r2) < (unsigned)H_);
        const float f0 = ok ? yv0[it] : 0.f;
        const float f1 = ok ? yv1[it] : 0.f;
        const int v = (int)(unsigned short)f2bf(f0) |
                      ((int)(unsigned short)f2bf(f1) << 16);
        ((int*)&xs[6 + r2][q + 1][0])[cp] = v;
    }
    if (tid < 128) {
        const int side = tid & 1;
        const int hrc  = tid >> 1;
        const int hcp  = hrc & 15;
        const int hr2  = hrc >> 4;                   // 0..3
        const int hrow = h0 + 5 + hr2;
        const int hwx  = wseg - 1 + side * 65;
        const bool hok = ((unsigned)hrow < (unsigned)H_) &&
                         ((unsigned)hwx  < (unsigned)W_);
        const float f0 = hok ? hw0 : 0.f;
        const float f1 = hok ? hw1 : 0.f;
        const int v = (int)(unsigned short)f2bf(f0) |
                      ((int)(unsigned short)f2bf(f1) << 16);
        ((int*)&xs[6 + hr2][side * 65][0])[hcp] = v;
    }
    {
        const int r0 = tid / 66;                     // 0..3
        const int q0 = tid - r0 * 66;
        const bool ok0 = ((unsigned)(h0 + 5 + r0) < (unsigned)H_) &&
                         ((unsigned)(wseg - 1 + q0) < (unsigned)W_);
        dsh[6 + r0][q0] = ok0 ? dw0 : 0.f;
        const int k1 = tid + 256;
        if (k1 < 264) {
            const int r1 = k1 / 66;                  // 3
            const int q1 = k1 - r1 * 66;
            const bool ok1 = ((unsigned)(h0 + 5 + r1) < (unsigned)H_) &&
                             ((unsigned)(wseg - 1 + q1) < (unsigned)W_);
            dsh[6 + r1][q1] = ok1 ? dw1 : 0.f;
        }
    }
    __syncthreads();   // xs rows 6..9 + dsh rows 6..9 ready

    // ========== COMPUTE TILE B (out rows h0+4..h0+7) ==========
    {
        const int rl   = w + 5;
        const int hrow = h0 + 4 + w;
#pragma unroll
        for (int sub = 0; sub < 4; ++sub) {
            const int pl = sub * 16 + n + 1;
            const int wp = wseg + sub * 16 + n;
            const float dc = dsh[rl][pl];

            float s[KTAPS];
#pragma unroll
            for (int ij = 0; ij < KTAPS; ++ij) {
                const int di = ij / 3 - 1;
                const int dj = ij % 3 - 1;
                const bool ok = ((unsigned)(hrow + di) < (unsigned)H_) &&
                                ((unsigned)(wp + dj) < (unsigned)W_);
                s[ij] = ok ? __expf(-ALPHA_F * fabsf(dc - dsh[rl + di][pl + dj])) : 0.f;
            }

            f32x4 acc0 = z, acc1 = z;
#pragma unroll
            for (int ij = 0; ij < KTAPS; ++ij) {
                const int di = ij / 3 - 1;
                const int dj = ij % 3 - 1;
                const bf16x8 bfrag = *(const bf16x8*)&xs[rl + di][pl + dj][cg];
                const f32x4 t0 = __builtin_amdgcn_mfma_f32_16x16x32_bf16(wa[ij * 2 + 0], bfrag, z, 0, 0, 0);
                const f32x4 t1 = __builtin_amdgcn_mfma_f32_16x16x32_bf16(wa[ij * 2 + 1], bfrag, z, 0, 0, 0);
#pragma unroll
                for (int j = 0; j < 4; ++j) {
                    acc0[j] = fmaf(s[ij], t0[j], acc0[j]);
                    acc1[j] = fmaf(s[ij], t1[j], acc1[j]);
                }
            }

            float* ob = out + (size_t)b * COUT * HW + hrow * W_ + wp;
#pragma unroll
            for (int j = 0; j < 4; ++j) {
                __builtin_nontemporal_store(acc0[j], ob + (size_t)(orow + j) * HW);
                __builtin_nontemporal_store(acc1[j], ob + (size_t)(orow + j + 16) * HW);
            }
        }
    }
}

// ---------- fp32 fallback (R1 kernel) ----------
__global__ __launch_bounds__(256)
void dconv_fallback(const float* __restrict__ x,
                    const float* __restrict__ depth,
                    const float* __restrict__ wgt,
                    float* __restrict__ out) {
    const int w  = threadIdx.x;
    const int bh = blockIdx.x;
    const int b  = bh >> 8;
    const int h  = bh & 255;

    const float* dplane = depth + (size_t)b * HW;
    const float  dc     = dplane[h * W_ + w];

    float acc[COUT];
#pragma unroll
    for (int o = 0; o < COUT; ++o) acc[o] = 0.f;

    const float* xb = x + (size_t)b * CIN * HW;

    for (int i = 0; i < 3; ++i) {
        const int  hh  = h + i - 1;
        const bool okh = ((unsigned)hh < (unsigned)H_);
        for (int j = 0; j < 3; ++j) {
            const int  ww = w + j - 1;
            const bool ok = okh && ((unsigned)ww < (unsigned)W_);
            const int  ij = i * 3 + j;
            const float dpv = ok ? dplane[hh * W_ + ww] : 0.f;
            const float sv  = __expf(-ALPHA_F * fabsf(dc - dpv));
            const int base = hh * W_ + ww;
#pragma unroll
            for (int c = 0; c < CIN; ++c) {
                const float v = (ok ? xb[c * HW + base] : 0.f) * sv;
#pragma unroll
                for (int o = 0; o < COUT; ++o) {
                    acc[o] = fmaf(v, wgt[(o * CIN + c) * KTAPS + ij], acc[o]);
                }
            }
        }
    }

    float* ob = out + ((size_t)b * COUT * H_ + h) * W_ + w;
#pragma unroll
    for (int o = 0; o < COUT; ++o) ob[o * HW] = acc[o];
}

extern "C" void kernel_launch(void* const* d_in, const int* in_sizes, int n_in,
                              void* d_out, int out_size, void* d_ws, size_t ws_size,
                              hipStream_t stream) {
    const float* x     = (const float*)d_in[0];
    const float* depth = (const float*)d_in[1];
    const float* wgt   = (const float*)d_in[2];
    float*       out   = (float*)d_out;

    const size_t wf_bytes = (size_t)(KTAPS * 2 * 64 * 8) * sizeof(short); // 18 KB

    if (ws_size >= wf_bytes) {
        short* wf = (short*)d_ws;
        prep_wfrag<<<(KTAPS * 2 * 64 * 8 + 255) / 256, 256, 0, stream>>>(wgt, wf);
        dconv_fused10<<<512, 256, 0, stream>>>(x, depth, wf, out);
    } else {
        dconv_fallback<<<B_ * H_, 256, 0, stream>>>(x, depth, wgt, out);
    }
}